// Round 1
// baseline (341.178 us; speedup 1.0000x reference)
//
#include <hip/hip_runtime.h>
#include <hip/hip_bf16.h>

#define B_    32
#define C_    256
#define H_    56
#define W_    56
#define HW_   3136
#define P_    58          // padded spatial (halo of 1)
#define G_    8
#define COUT_ 256
#define KTOT_ 2304        // 256 * 9

typedef float f32x4 __attribute__((ext_vector_type(4)));
typedef int   i32x4 __attribute__((ext_vector_type(4)));

// ---------------------------------------------------------------------------
// Kernel 1: GroupNorm statistics. One block per (b,g); 1024 threads
// (16 waves -> 4 waves/SIMD) for MLP on the 400KB/block contiguous read.
// ---------------------------------------------------------------------------
__global__ __launch_bounds__(1024)
void gn_stats_kernel(const float* __restrict__ x, float* __restrict__ stats) {
    int bg = blockIdx.x;                       // b*8 + g
    const float4* base = (const float4*)(x + (size_t)bg * (32 * HW_));
    float s1 = 0.f, s2 = 0.f;
    for (int i = threadIdx.x; i < 25088; i += 1024) {   // 100352 floats / 4
        float4 v = base[i];
        s1 += v.x + v.y + v.z + v.w;
        s2 += v.x * v.x + v.y * v.y + v.z * v.z + v.w * v.w;
    }
    #pragma unroll
    for (int off = 32; off; off >>= 1) {
        s1 += __shfl_down(s1, off, 64);
        s2 += __shfl_down(s2, off, 64);
    }
    __shared__ float ra[16], rb[16];
    int lane = threadIdx.x & 63, wv = threadIdx.x >> 6;
    if (!lane) { ra[wv] = s1; rb[wv] = s2; }
    __syncthreads();
    if (threadIdx.x == 0) {
        float t1 = 0.f, t2 = 0.f;
        #pragma unroll
        for (int i = 0; i < 16; ++i) { t1 += ra[i]; t2 += rb[i]; }
        float mu = t1 / 100352.f;
        float var = t2 / 100352.f - mu * mu;
        stats[bg * 2]     = mu;
        stats[bg * 2 + 1] = rsqrtf(var + 1e-5f);
    }
}

// ---------------------------------------------------------------------------
// Kernel 2 (v3): GN + ReLU^2 + PACT quant -> zero-padded NHWC int8 buffer.
// Stores qs = round(q) - 128 in [-128,127]; halo = -128 (consistent with the
// epilogue correction  sum(q*t) = acc + 128*T[oc]).  Register 4x4 transpose:
// thread owns 4 channels (c4 = tid&63; wave spans all 256 ch) x float4
// w-blocks; stores are packed 4B ints, 256B contiguous per wave instruction.
// ---------------------------------------------------------------------------
__global__ __launch_bounds__(256)
void act_kernel(const float* __restrict__ x, const float* __restrict__ gamma,
                const float* __restrict__ beta, const float* __restrict__ a_ptr,
                const float* __restrict__ stats, char* __restrict__ q) {
    int by = blockIdx.x;                 // b*58 + y
    int b = by / P_;
    int y = by - b * P_;
    char* qrow = q + (size_t)by * P_ * C_;
    const int PADV = 0x80808080;         // four -128 bytes
    if (y == 0 || y == P_ - 1) {
        int4 pv = {PADV, PADV, PADV, PADV};
        for (int i = threadIdx.x; i < (P_ * C_) / 16; i += 256)
            ((int4*)qrow)[i] = pv;
        return;
    }
    int t = threadIdx.x;
    // halo columns (pixel 0 and 57): 64 ints each
    if (t < 64)            ((int*)qrow)[t] = PADV;
    else if (t < 128)      ((int*)(qrow + (P_ - 1) * C_))[t - 64] = PADV;

    float a_c = fmaxf(a_ptr[0], 0.f) + 1e-8f;
    float S   = 255.f / a_c;

    int c4 = t & 63;                     // channels 4*c4 .. 4*c4+3 (same group)
    int wb = t >> 6;                     // starting w-block
    int g  = (4 * c4) >> 5;
    float mu = stats[(b * G_ + g) * 2];
    float rs = stats[(b * G_ + g) * 2 + 1];
    float ga[4], be[4];
    #pragma unroll
    for (int i = 0; i < 4; ++i) { ga[i] = gamma[4 * c4 + i]; be[i] = beta[4 * c4 + i]; }

    const float* xb = x + ((size_t)(b * C_ + 4 * c4)) * HW_ + (y - 1) * W_;
    for (int j = wb; j < 14; j += 4) {
        float4 v[4];
        #pragma unroll
        for (int i = 0; i < 4; ++i)
            v[i] = *(const float4*)(xb + (size_t)i * HW_ + j * 4);
        int qv[4][4];
        #pragma unroll
        for (int i = 0; i < 4; ++i) {
            float f[4] = {v[i].x, v[i].y, v[i].z, v[i].w};
            #pragma unroll
            for (int s = 0; s < 4; ++s) {
                float yv = (f[s] - mu) * rs * ga[i] + be[i];
                float r  = fmaxf(yv, 0.f);
                float h2 = fminf(r * r, a_c);
                qv[i][s] = (int)rintf(h2 * S) - 128;
            }
        }
        #pragma unroll
        for (int s = 0; s < 4; ++s) {
            int packed = (qv[0][s] & 255) | ((qv[1][s] & 255) << 8) |
                         ((qv[2][s] & 255) << 16) | (qv[3][s] << 24);
            *(int*)(qrow + (j * 4 + s + 1) * C_ + 4 * c4) = packed;
        }
    }
}

// ---------------------------------------------------------------------------
// Kernel 3: ternary weight prep. One block per oc. Writes wt[tap][oc][ic]
// as int8 {-1,0,+1}, alpha[oc], and tsum[oc] = sum_k t[oc,k] (epilogue
// correction for the -128 activation shift).
// ---------------------------------------------------------------------------
__global__ __launch_bounds__(256)
void wq_kernel(const float* __restrict__ wfp, char* __restrict__ wt,
               float* __restrict__ alphas, float* __restrict__ tsum) {
    int oc = blockIdx.x;
    int t  = threadIdx.x;
    const float* wr = wfp + (size_t)oc * KTOT_;
    float wl[9];
    float s = 0.f;
    #pragma unroll
    for (int j = 0; j < 9; ++j) { wl[j] = wr[t + j * 256]; s += fabsf(wl[j]); }

    __shared__ float red[4];
    int lane = t & 63, wv = t >> 6;
    #pragma unroll
    for (int off = 32; off; off >>= 1) s += __shfl_down(s, off, 64);
    if (!lane) red[wv] = s;
    __syncthreads();
    float thr = 0.05f * ((red[0] + red[1] + red[2] + red[3]) / (float)KTOT_);
    __syncthreads();

    float sm = 0.f, cnt = 0.f, ts = 0.f;
    #pragma unroll
    for (int j = 0; j < 9; ++j) {
        float aw = fabsf(wl[j]);
        if (aw > thr) {
            sm += aw; cnt += 1.f;
            ts += (wl[j] > 0.f) ? 1.f : -1.f;
        }
    }
    #pragma unroll
    for (int off = 32; off; off >>= 1) {
        sm  += __shfl_down(sm, off, 64);
        cnt += __shfl_down(cnt, off, 64);
        ts  += __shfl_down(ts, off, 64);
    }
    __shared__ float redc[4], redt[4];
    if (!lane) { red[wv] = sm; redc[wv] = cnt; redt[wv] = ts; }
    __syncthreads();
    if (t == 0) {
        float alpha = (red[0] + red[1] + red[2] + red[3]) /
                      (redc[0] + redc[1] + redc[2] + redc[3] + 1e-8f);
        alphas[oc] = alpha;
        tsum[oc] = redt[0] + redt[1] + redt[2] + redt[3];
    }
    #pragma unroll
    for (int j = 0; j < 9; ++j) {
        int i  = t + j * 256;           // i = ic*9 + tap
        int ic = i / 9;
        int tap = i - ic * 9;
        float w = wl[j];
        char tern = (fabsf(w) > thr) ? (w > 0.f ? (char)1 : (char)-1) : (char)0;
        wt[((size_t)tap * 256 + oc) * 256 + ic] = tern;
    }
}

// ---------------------------------------------------------------------------
// Kernel 4 (v2: 8-phase-style pipelined schedule, T3+T4+T5):
// implicit-GEMM conv, i8 MFMA. M=100352, N=256 (full N per block), K=9*256.
// 128x256 block tile, BK=128, double-buffered LDS (96KB -> 1 block/CU).
// 512 threads = 8 waves (2x4 of 64x64), mfma_i32_16x16x64_i8.
// Per K-tile: 4 phases, each {issue 1/3 of next tile's staging || ds_read one
// fragment subtile -> setprio(1) -> 8 MFMA -> setprio(0) -> s_barrier}.
// vmcnt(0) drain only ONCE per K-tile (the final __syncthreads), so the 6
// prefetch loads stay in flight across ~3 phases of MFMA (counted-wait idea).
// Exact integer arithmetic; epilogue adds 128*tsum[oc] shift correction.
// ---------------------------------------------------------------------------
__global__ __launch_bounds__(512)
void conv_gemm_kernel(const char* __restrict__ q, const char* __restrict__ wt,
                      const float* __restrict__ alphas, const float* __restrict__ bias,
                      const float* __restrict__ tsum, const float* __restrict__ a_ptr,
                      float* __restrict__ out) {
    int mt = blockIdx.x;         // 784 M-tiles of 128
    int tid = threadIdx.x;       // 0..511
    int lane = tid & 63;
    int wv = tid >> 6;           // 0..7
    int wm = wv & 1, wn = wv >> 1;          // 2 m-halves x 4 n-quarters
    int quad = lane >> 4, lrow = lane & 15;

    __shared__ char As[2][128 * 128];   // 2 x 16 KB
    __shared__ char Bs[2][256 * 128];   // 2 x 32 KB

    // XOR bank swizzle on 16B K-blocks: slot kb holds global kb ^ (row&7)
    int kswz = (((tid & 7) ^ ((tid >> 3) & 7)) << 4);
    int sb[2], wb[4];
    #pragma unroll
    for (int r = 0; r < 2; ++r) {
        int ml = r * 64 + (tid >> 3);
        int m = mt * 128 + ml;
        int b = m / HW_;
        int rem = m - b * HW_;
        int hh = rem / W_;
        int ww = rem - hh * W_;
        sb[r] = ((b * P_ + hh + 1) * P_ + (ww + 1)) * C_ + kswz;
    }
    #pragma unroll
    for (int r = 0; r < 4; ++r) {
        int oc = r * 64 + (tid >> 3);
        wb[r] = oc * C_ + kswz;
    }

    i32x4 acc[4][4];
    #pragma unroll
    for (int i = 0; i < 4; ++i)
        #pragma unroll
        for (int j = 0; j < 4; ++j) { acc[i][j][0]=0; acc[i][j][1]=0; acc[i][j][2]=0; acc[i][j][3]=0; }

    int arow = wm * 64 + lrow;
    int brow = wn * 64 + lrow;
    int rsw = lrow & 7;          // read-side XOR key

    // --- staging helpers: tile kk -> buffer buf ------------------------------
    auto stageA = [&](int kk, int buf) {
        int tap = kk >> 1;
        int ic0 = (kk & 1) << 7;
        int dh = tap / 3 - 1;
        int dw = tap - (tap / 3) * 3 - 1;
        int aoff = (dh * P_ + dw) * C_ + ic0;
        #pragma unroll
        for (int r = 0; r < 2; ++r) {
            __builtin_amdgcn_global_load_lds(
                (const __attribute__((address_space(1))) void*)(q + sb[r] + aoff),
                (__attribute__((address_space(3))) void*)(&As[buf][r * 8192 + tid * 16]),
                16, 0, 0);
        }
    };
    auto stageB = [&](int kk, int buf, int half) {
        int tap = kk >> 1;
        int ic0 = (kk & 1) << 7;
        const char* gb = wt + (size_t)tap * (256 * 256) + ic0;
        #pragma unroll
        for (int r = 0; r < 2; ++r) {
            int rr = half * 2 + r;
            __builtin_amdgcn_global_load_lds(
                (const __attribute__((address_space(1))) void*)(gb + wb[rr]),
                (__attribute__((address_space(3))) void*)(&Bs[buf][rr * 8192 + tid * 16]),
                16, 0, 0);
        }
    };

    // prologue: stage tile 0 fully, drain, barrier
    stageA(0, 0);
    stageB(0, 0, 0);
    stageB(0, 0, 1);
    __syncthreads();

    int cur = 0;
    for (int kk = 0; kk < 18; ++kk) {
        int nxt = cur ^ 1;
        bool pf = (kk < 17);
        i32x4 bf[4];

        // ---- phase 0: ks=0, mi{0,1}; prefetch A(kk+1) -----------------------
        if (pf) stageA(kk + 1, nxt);
        {
            int cb = quad ^ rsw;                 // ks=0
            #pragma unroll
            for (int ni = 0; ni < 4; ++ni)
                bf[ni] = *(const i32x4*)&Bs[cur][(brow + ni * 16) * 128 + cb * 16];
            i32x4 a0 = *(const i32x4*)&As[cur][(arow +  0) * 128 + cb * 16];
            i32x4 a1 = *(const i32x4*)&As[cur][(arow + 16) * 128 + cb * 16];
            __builtin_amdgcn_s_setprio(1);
            #pragma unroll
            for (int ni = 0; ni < 4; ++ni)
                acc[0][ni] = __builtin_amdgcn_mfma_i32_16x16x64_i8(a0, bf[ni], acc[0][ni], 0, 0, 0);
            #pragma unroll
            for (int ni = 0; ni < 4; ++ni)
                acc[1][ni] = __builtin_amdgcn_mfma_i32_16x16x64_i8(a1, bf[ni], acc[1][ni], 0, 0, 0);
            __builtin_amdgcn_s_setprio(0);
        }
        __builtin_amdgcn_s_barrier();

        // ---- phase 1: ks=0, mi{2,3}; prefetch B(kk+1) half 0 ---------------
        if (pf) stageB(kk + 1, nxt, 0);
        {
            int cb = quad ^ rsw;
            i32x4 a2 = *(const i32x4*)&As[cur][(arow + 32) * 128 + cb * 16];
            i32x4 a3 = *(const i32x4*)&As[cur][(arow + 48) * 128 + cb * 16];
            __builtin_amdgcn_s_setprio(1);
            #pragma unroll
            for (int ni = 0; ni < 4; ++ni)
                acc[2][ni] = __builtin_amdgcn_mfma_i32_16x16x64_i8(a2, bf[ni], acc[2][ni], 0, 0, 0);
            #pragma unroll
            for (int ni = 0; ni < 4; ++ni)
                acc[3][ni] = __builtin_amdgcn_mfma_i32_16x16x64_i8(a3, bf[ni], acc[3][ni], 0, 0, 0);
            __builtin_amdgcn_s_setprio(0);
        }
        __builtin_amdgcn_s_barrier();

        // ---- phase 2: ks=1, mi{0,1}; prefetch B(kk+1) half 1 ---------------
        if (pf) stageB(kk + 1, nxt, 1);
        {
            int cb = (4 + quad) ^ rsw;           // ks=1
            #pragma unroll
            for (int ni = 0; ni < 4; ++ni)
                bf[ni] = *(const i32x4*)&Bs[cur][(brow + ni * 16) * 128 + cb * 16];
            i32x4 a0 = *(const i32x4*)&As[cur][(arow +  0) * 128 + cb * 16];
            i32x4 a1 = *(const i32x4*)&As[cur][(arow + 16) * 128 + cb * 16];
            __builtin_amdgcn_s_setprio(1);
            #pragma unroll
            for (int ni = 0; ni < 4; ++ni)
                acc[0][ni] = __builtin_amdgcn_mfma_i32_16x16x64_i8(a0, bf[ni], acc[0][ni], 0, 0, 0);
            #pragma unroll
            for (int ni = 0; ni < 4; ++ni)
                acc[1][ni] = __builtin_amdgcn_mfma_i32_16x16x64_i8(a1, bf[ni], acc[1][ni], 0, 0, 0);
            __builtin_amdgcn_s_setprio(0);
        }
        __builtin_amdgcn_s_barrier();

        // ---- phase 3: ks=1, mi{2,3}; no staging; full drain + swap ---------
        {
            int cb = (4 + quad) ^ rsw;
            i32x4 a2 = *(const i32x4*)&As[cur][(arow + 32) * 128 + cb * 16];
            i32x4 a3 = *(const i32x4*)&As[cur][(arow + 48) * 128 + cb * 16];
            __builtin_amdgcn_s_setprio(1);
            #pragma unroll
            for (int ni = 0; ni < 4; ++ni)
                acc[2][ni] = __builtin_amdgcn_mfma_i32_16x16x64_i8(a2, bf[ni], acc[2][ni], 0, 0, 0);
            #pragma unroll
            for (int ni = 0; ni < 4; ++ni)
                acc[3][ni] = __builtin_amdgcn_mfma_i32_16x16x64_i8(a3, bf[ni], acc[3][ni], 0, 0, 0);
            __builtin_amdgcn_s_setprio(0);
        }
        __syncthreads();     // vmcnt(0) lgkmcnt(0) + barrier: next tile ready
        cur = nxt;
    }

    float a_c = fmaxf(a_ptr[0], 0.f) + 1e-8f;
    float qs  = a_c * (1.f / 255.f);
    #pragma unroll
    for (int ni = 0; ni < 4; ++ni) {
        int n = wn * 64 + ni * 16 + lrow;
        float sc = alphas[n] * qs;
        float bn = bias[n];
        float corr = 128.f * tsum[n];       // undo the -128 activation shift
        #pragma unroll
        for (int mi = 0; mi < 4; ++mi) {
            int mbase = mt * 128 + wm * 64 + mi * 16 + quad * 4;
            int b = mbase / HW_;
            size_t off = (size_t)b * (C_ * HW_) + (size_t)n * HW_ + (mbase - b * HW_);
            f32x4 v;
            #pragma unroll
            for (int r = 0; r < 4; ++r)
                v[r] = ((float)acc[mi][ni][r] + corr) * sc + bn;
            *(f32x4*)(out + off) = v;
        }
    }
}

// ---------------------------------------------------------------------------
extern "C" void kernel_launch(void* const* d_in, const int* in_sizes, int n_in,
                              void* d_out, int out_size, void* d_ws, size_t ws_size,
                              hipStream_t stream) {
    const float* x     = (const float*)d_in[0];
    const float* gamma = (const float*)d_in[1];
    const float* beta  = (const float*)d_in[2];
    const float* a     = (const float*)d_in[3];
    const float* wfp   = (const float*)d_in[4];
    const float* bias  = (const float*)d_in[5];
    float* out = (float*)d_out;

    char* ws = (char*)d_ws;
    char*  qbuf   = ws;                                        // 32*58*58*256 i8 = 27,557,888 B
    char*  wtb    = ws + 27557888;                             // 9*256*256 i8  = 589,824 B
    float* alphas = (float*)(ws + 27557888 + 589824);          // 256 fp32
    float* tsum   = alphas + 256;                              // 256 fp32
    float* stats  = tsum + 256;                                // 512 fp32 (mu, rs)

    gn_stats_kernel<<<B_ * G_, 1024, 0, stream>>>(x, stats);
    wq_kernel<<<COUT_, 256, 0, stream>>>(wfp, wtb, alphas, tsum);
    act_kernel<<<B_ * P_, 256, 0, stream>>>(x, gamma, beta, a, stats, qbuf);
    conv_gemm_kernel<<<784, 512, 0, stream>>>(qbuf, wtb, alphas, bias, tsum, a, out);
}

// Round 2
// 316.907 us; speedup vs baseline: 1.0766x; 1.0766x over previous
//
#include <hip/hip_runtime.h>
#include <hip/hip_bf16.h>

#define B_    32
#define C_    256
#define H_    56
#define W_    56
#define HW_   3136
#define P_    58          // padded spatial (halo of 1)
#define G_    8
#define COUT_ 256
#define KTOT_ 2304        // 256 * 9

typedef float f32x4 __attribute__((ext_vector_type(4)));
typedef int   i32x4 __attribute__((ext_vector_type(4)));

// ---------------------------------------------------------------------------
// Kernel 1: GroupNorm statistics. One block per (b,g); 1024 threads
// (16 waves -> 4 waves/SIMD) for MLP on the 400KB/block contiguous read.
// ---------------------------------------------------------------------------
__global__ __launch_bounds__(1024)
void gn_stats_kernel(const float* __restrict__ x, float* __restrict__ stats) {
    int bg = blockIdx.x;                       // b*8 + g
    const float4* base = (const float4*)(x + (size_t)bg * (32 * HW_));
    float s1 = 0.f, s2 = 0.f;
    for (int i = threadIdx.x; i < 25088; i += 1024) {   // 100352 floats / 4
        float4 v = base[i];
        s1 += v.x + v.y + v.z + v.w;
        s2 += v.x * v.x + v.y * v.y + v.z * v.z + v.w * v.w;
    }
    #pragma unroll
    for (int off = 32; off; off >>= 1) {
        s1 += __shfl_down(s1, off, 64);
        s2 += __shfl_down(s2, off, 64);
    }
    __shared__ float ra[16], rb[16];
    int lane = threadIdx.x & 63, wv = threadIdx.x >> 6;
    if (!lane) { ra[wv] = s1; rb[wv] = s2; }
    __syncthreads();
    if (threadIdx.x == 0) {
        float t1 = 0.f, t2 = 0.f;
        #pragma unroll
        for (int i = 0; i < 16; ++i) { t1 += ra[i]; t2 += rb[i]; }
        float mu = t1 / 100352.f;
        float var = t2 / 100352.f - mu * mu;
        stats[bg * 2]     = mu;
        stats[bg * 2 + 1] = rsqrtf(var + 1e-5f);
    }
}

// ---------------------------------------------------------------------------
// Kernel 2 (v3): GN + ReLU^2 + PACT quant -> zero-padded NHWC int8 buffer.
// Stores qs = round(q) - 128 in [-128,127]; halo = -128 (consistent with the
// epilogue correction  sum(q*t) = acc + 128*T[oc]).  Register 4x4 transpose:
// thread owns 4 channels (c4 = tid&63; wave spans all 256 ch) x float4
// w-blocks; stores are packed 4B ints, 256B contiguous per wave instruction.
// ---------------------------------------------------------------------------
__global__ __launch_bounds__(256)
void act_kernel(const float* __restrict__ x, const float* __restrict__ gamma,
                const float* __restrict__ beta, const float* __restrict__ a_ptr,
                const float* __restrict__ stats, char* __restrict__ q) {
    int by = blockIdx.x;                 // b*58 + y
    int b = by / P_;
    int y = by - b * P_;
    char* qrow = q + (size_t)by * P_ * C_;
    const int PADV = 0x80808080;         // four -128 bytes
    if (y == 0 || y == P_ - 1) {
        int4 pv = {PADV, PADV, PADV, PADV};
        for (int i = threadIdx.x; i < (P_ * C_) / 16; i += 256)
            ((int4*)qrow)[i] = pv;
        return;
    }
    int t = threadIdx.x;
    // halo columns (pixel 0 and 57): 64 ints each
    if (t < 64)            ((int*)qrow)[t] = PADV;
    else if (t < 128)      ((int*)(qrow + (P_ - 1) * C_))[t - 64] = PADV;

    float a_c = fmaxf(a_ptr[0], 0.f) + 1e-8f;
    float S   = 255.f / a_c;

    int c4 = t & 63;                     // channels 4*c4 .. 4*c4+3 (same group)
    int wb = t >> 6;                     // starting w-block
    int g  = (4 * c4) >> 5;
    float mu = stats[(b * G_ + g) * 2];
    float rs = stats[(b * G_ + g) * 2 + 1];
    float ga[4], be[4];
    #pragma unroll
    for (int i = 0; i < 4; ++i) { ga[i] = gamma[4 * c4 + i]; be[i] = beta[4 * c4 + i]; }

    const float* xb = x + ((size_t)(b * C_ + 4 * c4)) * HW_ + (y - 1) * W_;
    for (int j = wb; j < 14; j += 4) {
        float4 v[4];
        #pragma unroll
        for (int i = 0; i < 4; ++i)
            v[i] = *(const float4*)(xb + (size_t)i * HW_ + j * 4);
        int qv[4][4];
        #pragma unroll
        for (int i = 0; i < 4; ++i) {
            float f[4] = {v[i].x, v[i].y, v[i].z, v[i].w};
            #pragma unroll
            for (int s = 0; s < 4; ++s) {
                float yv = (f[s] - mu) * rs * ga[i] + be[i];
                float r  = fmaxf(yv, 0.f);
                float h2 = fminf(r * r, a_c);
                qv[i][s] = (int)rintf(h2 * S) - 128;
            }
        }
        #pragma unroll
        for (int s = 0; s < 4; ++s) {
            int packed = (qv[0][s] & 255) | ((qv[1][s] & 255) << 8) |
                         ((qv[2][s] & 255) << 16) | (qv[3][s] << 24);
            *(int*)(qrow + (j * 4 + s + 1) * C_ + 4 * c4) = packed;
        }
    }
}

// ---------------------------------------------------------------------------
// Kernel 3: ternary weight prep. One block per oc. Writes wt[tap][oc][ic]
// as int8 {-1,0,+1}, alpha[oc], and tsum[oc] = sum_k t[oc,k] (epilogue
// correction for the -128 activation shift).
// ---------------------------------------------------------------------------
__global__ __launch_bounds__(256)
void wq_kernel(const float* __restrict__ wfp, char* __restrict__ wt,
               float* __restrict__ alphas, float* __restrict__ tsum) {
    int oc = blockIdx.x;
    int t  = threadIdx.x;
    const float* wr = wfp + (size_t)oc * KTOT_;
    float wl[9];
    float s = 0.f;
    #pragma unroll
    for (int j = 0; j < 9; ++j) { wl[j] = wr[t + j * 256]; s += fabsf(wl[j]); }

    __shared__ float red[4];
    int lane = t & 63, wv = t >> 6;
    #pragma unroll
    for (int off = 32; off; off >>= 1) s += __shfl_down(s, off, 64);
    if (!lane) red[wv] = s;
    __syncthreads();
    float thr = 0.05f * ((red[0] + red[1] + red[2] + red[3]) / (float)KTOT_);
    __syncthreads();

    float sm = 0.f, cnt = 0.f, ts = 0.f;
    #pragma unroll
    for (int j = 0; j < 9; ++j) {
        float aw = fabsf(wl[j]);
        if (aw > thr) {
            sm += aw; cnt += 1.f;
            ts += (wl[j] > 0.f) ? 1.f : -1.f;
        }
    }
    #pragma unroll
    for (int off = 32; off; off >>= 1) {
        sm  += __shfl_down(sm, off, 64);
        cnt += __shfl_down(cnt, off, 64);
        ts  += __shfl_down(ts, off, 64);
    }
    __shared__ float redc[4], redt[4];
    if (!lane) { red[wv] = sm; redc[wv] = cnt; redt[wv] = ts; }
    __syncthreads();
    if (t == 0) {
        float alpha = (red[0] + red[1] + red[2] + red[3]) /
                      (redc[0] + redc[1] + redc[2] + redc[3] + 1e-8f);
        alphas[oc] = alpha;
        tsum[oc] = redt[0] + redt[1] + redt[2] + redt[3];
    }
    #pragma unroll
    for (int j = 0; j < 9; ++j) {
        int i  = t + j * 256;           // i = ic*9 + tap
        int ic = i / 9;
        int tap = i - ic * 9;
        float w = wl[j];
        char tern = (fabsf(w) > thr) ? (w > 0.f ? (char)1 : (char)-1) : (char)0;
        wt[((size_t)tap * 256 + oc) * 256 + ic] = tern;
    }
}

// ---------------------------------------------------------------------------
// Kernel 4 (v3: T3-minimum 2-phase double-buffered pipeline):
// implicit-GEMM conv, i8 MFMA. M=100352, N=256 (full N per block), K=9*256.
// 128x256 block tile, BK=128, double-buffered LDS (96KB -> 1 block/CU).
// Per K-tile: issue the ENTIRE next tile's staging (6 global_load_lds) at the
// TOP, then ds_read + 32 MFMA/wave on the current buffer, then ONE
// __syncthreads (vmcnt(0)+lgkmcnt(0)+barrier) at the END. The drain thus
// waits on loads issued a full tile (~330 cyc of MFMA) earlier -- covered
// for L2-resident wt/qbuf. (Round-1 failure: drain had only 1 phase of
// cover + 4 barriers/tile.) Grid 784 = 8*98: bijective XCD-chunked swizzle
// puts 98 consecutive M-tiles (contiguous ~3.4MB qbuf span + halo overlap)
// on one XCD's 4MB L2. Exact integer arithmetic; epilogue adds 128*tsum[oc].
// ---------------------------------------------------------------------------
__global__ __launch_bounds__(512)
void conv_gemm_kernel(const char* __restrict__ q, const char* __restrict__ wt,
                      const float* __restrict__ alphas, const float* __restrict__ bias,
                      const float* __restrict__ tsum, const float* __restrict__ a_ptr,
                      float* __restrict__ out) {
    int bid = blockIdx.x;
    int mt = (bid & 7) * 98 + (bid >> 3);   // XCD swizzle: 784 = 8*98 (bijective)
    int tid = threadIdx.x;       // 0..511
    int lane = tid & 63;
    int wv = tid >> 6;           // 0..7
    int wm = wv & 1, wn = wv >> 1;          // 2 m-halves x 4 n-quarters
    int quad = lane >> 4, lrow = lane & 15;

    __shared__ char As[2][128 * 128];   // 2 x 16 KB
    __shared__ char Bs[2][256 * 128];   // 2 x 32 KB

    // XOR bank swizzle on 16B K-blocks: slot kb holds global kb ^ (row&7)
    int kswz = (((tid & 7) ^ ((tid >> 3) & 7)) << 4);
    int sb[2], wb[4];
    #pragma unroll
    for (int r = 0; r < 2; ++r) {
        int ml = r * 64 + (tid >> 3);
        int m = mt * 128 + ml;
        int b = m / HW_;
        int rem = m - b * HW_;
        int hh = rem / W_;
        int ww = rem - hh * W_;
        sb[r] = ((b * P_ + hh + 1) * P_ + (ww + 1)) * C_ + kswz;
    }
    #pragma unroll
    for (int r = 0; r < 4; ++r) {
        int oc = r * 64 + (tid >> 3);
        wb[r] = oc * C_ + kswz;
    }

    i32x4 acc[4][4];
    #pragma unroll
    for (int i = 0; i < 4; ++i)
        #pragma unroll
        for (int j = 0; j < 4; ++j) { acc[i][j][0]=0; acc[i][j][1]=0; acc[i][j][2]=0; acc[i][j][3]=0; }

    int arow = wm * 64 + lrow;
    int brow = wn * 64 + lrow;
    int rsw = lrow & 7;          // read-side XOR key

    // full-tile staging: 6 global_load_lds (2 A + 4 B) into buffer buf
    auto stage = [&](int kk, int buf) {
        int tap = kk >> 1;
        int ic0 = (kk & 1) << 7;
        int dh = tap / 3 - 1;
        int dw = tap - (tap / 3) * 3 - 1;
        int aoff = (dh * P_ + dw) * C_ + ic0;
        #pragma unroll
        for (int r = 0; r < 2; ++r) {
            __builtin_amdgcn_global_load_lds(
                (const __attribute__((address_space(1))) void*)(q + sb[r] + aoff),
                (__attribute__((address_space(3))) void*)(&As[buf][r * 8192 + tid * 16]),
                16, 0, 0);
        }
        const char* gb = wt + (size_t)tap * (256 * 256) + ic0;
        #pragma unroll
        for (int r = 0; r < 4; ++r) {
            __builtin_amdgcn_global_load_lds(
                (const __attribute__((address_space(1))) void*)(gb + wb[r]),
                (__attribute__((address_space(3))) void*)(&Bs[buf][r * 8192 + tid * 16]),
                16, 0, 0);
        }
    };

    // prologue: stage tile 0, drain, barrier
    stage(0, 0);
    __syncthreads();

    int cur = 0;
    for (int kk = 0; kk < 18; ++kk) {
        int nxt = cur ^ 1;
        // issue next tile's staging FIRST -- a full tile of MFMA covers it
        if (kk < 17) stage(kk + 1, nxt);
        // compute current tile (round-0 inner loop, compiler-scheduled)
        #pragma unroll
        for (int ks = 0; ks < 2; ++ks) {
            int cb = (ks * 4 + quad) ^ rsw;
            i32x4 af[4], bf[4];
            #pragma unroll
            for (int mi = 0; mi < 4; ++mi)
                af[mi] = *(const i32x4*)&As[cur][(arow + mi * 16) * 128 + cb * 16];
            #pragma unroll
            for (int ni = 0; ni < 4; ++ni)
                bf[ni] = *(const i32x4*)&Bs[cur][(brow + ni * 16) * 128 + cb * 16];
            #pragma unroll
            for (int mi = 0; mi < 4; ++mi)
                #pragma unroll
                for (int ni = 0; ni < 4; ++ni)
                    acc[mi][ni] = __builtin_amdgcn_mfma_i32_16x16x64_i8(
                        af[mi], bf[ni], acc[mi][ni], 0, 0, 0);
        }
        __syncthreads();   // ONE drain per tile: vmcnt(0)+lgkmcnt(0)+barrier
        cur = nxt;
    }

    float a_c = fmaxf(a_ptr[0], 0.f) + 1e-8f;
    float qs  = a_c * (1.f / 255.f);
    #pragma unroll
    for (int ni = 0; ni < 4; ++ni) {
        int n = wn * 64 + ni * 16 + lrow;
        float sc = alphas[n] * qs;
        float bn = bias[n];
        float corr = 128.f * tsum[n];       // undo the -128 activation shift
        #pragma unroll
        for (int mi = 0; mi < 4; ++mi) {
            int mbase = mt * 128 + wm * 64 + mi * 16 + quad * 4;
            int b = mbase / HW_;
            size_t off = (size_t)b * (C_ * HW_) + (size_t)n * HW_ + (mbase - b * HW_);
            f32x4 v;
            #pragma unroll
            for (int r = 0; r < 4; ++r)
                v[r] = ((float)acc[mi][ni][r] + corr) * sc + bn;
            *(f32x4*)(out + off) = v;
        }
    }
}

// ---------------------------------------------------------------------------
extern "C" void kernel_launch(void* const* d_in, const int* in_sizes, int n_in,
                              void* d_out, int out_size, void* d_ws, size_t ws_size,
                              hipStream_t stream) {
    const float* x     = (const float*)d_in[0];
    const float* gamma = (const float*)d_in[1];
    const float* beta  = (const float*)d_in[2];
    const float* a     = (const float*)d_in[3];
    const float* wfp   = (const float*)d_in[4];
    const float* bias  = (const float*)d_in[5];
    float* out = (float*)d_out;

    char* ws = (char*)d_ws;
    char*  qbuf   = ws;                                        // 32*58*58*256 i8 = 27,557,888 B
    char*  wtb    = ws + 27557888;                             // 9*256*256 i8  = 589,824 B
    float* alphas = (float*)(ws + 27557888 + 589824);          // 256 fp32
    float* tsum   = alphas + 256;                              // 256 fp32
    float* stats  = tsum + 256;                                // 512 fp32 (mu, rs)

    gn_stats_kernel<<<B_ * G_, 1024, 0, stream>>>(x, stats);
    wq_kernel<<<COUT_, 256, 0, stream>>>(wfp, wtb, alphas, tsum);
    act_kernel<<<B_ * P_, 256, 0, stream>>>(x, gamma, beta, a, stats, qbuf);
    conv_gemm_kernel<<<784, 512, 0, stream>>>(qbuf, wtb, alphas, bias, tsum, a, out);
}

// Round 3
// 280.155 us; speedup vs baseline: 1.2178x; 1.1312x over previous
//
#include <hip/hip_runtime.h>
#include <hip/hip_bf16.h>

#define B_    32
#define C_    256
#define H_    56
#define W_    56
#define HW_   3136
#define P_    58          // padded spatial (halo of 1)
#define G_    8
#define COUT_ 256
#define KTOT_ 2304        // 256 * 9

typedef float f32x4 __attribute__((ext_vector_type(4)));
typedef int   i32x4 __attribute__((ext_vector_type(4)));

// ---------------------------------------------------------------------------
// Kernel 1: GroupNorm statistics. One block per (b,g); 1024 threads
// (16 waves -> 4 waves/SIMD) for MLP on the 400KB/block contiguous read.
// ---------------------------------------------------------------------------
__global__ __launch_bounds__(1024)
void gn_stats_kernel(const float* __restrict__ x, float* __restrict__ stats) {
    int bg = blockIdx.x;                       // b*8 + g
    const float4* base = (const float4*)(x + (size_t)bg * (32 * HW_));
    float s1 = 0.f, s2 = 0.f;
    for (int i = threadIdx.x; i < 25088; i += 1024) {   // 100352 floats / 4
        float4 v = base[i];
        s1 += v.x + v.y + v.z + v.w;
        s2 += v.x * v.x + v.y * v.y + v.z * v.z + v.w * v.w;
    }
    #pragma unroll
    for (int off = 32; off; off >>= 1) {
        s1 += __shfl_down(s1, off, 64);
        s2 += __shfl_down(s2, off, 64);
    }
    __shared__ float ra[16], rb[16];
    int lane = threadIdx.x & 63, wv = threadIdx.x >> 6;
    if (!lane) { ra[wv] = s1; rb[wv] = s2; }
    __syncthreads();
    if (threadIdx.x == 0) {
        float t1 = 0.f, t2 = 0.f;
        #pragma unroll
        for (int i = 0; i < 16; ++i) { t1 += ra[i]; t2 += rb[i]; }
        float mu = t1 / 100352.f;
        float var = t2 / 100352.f - mu * mu;
        stats[bg * 2]     = mu;
        stats[bg * 2 + 1] = rsqrtf(var + 1e-5f);
    }
}

// ---------------------------------------------------------------------------
// Kernel 2 (v4): GN + ReLU^2 + PACT quant -> zero-padded NHWC int8 buffer.
// v3's global read had 64 lanes strided 4*HW_ floats apart: every wave-load
// touched 64 distinct cache lines (TA address-serialization). v4 stages the
// whole (b, row y-1) slab -- 256 channels x 56 floats = 56KB -- into LDS with
// LINEAR chunk-indexed reads (consecutive lanes -> consecutive 16B), then
// runs the unchanged quant/register-transpose path out of LDS.
// LDS stride padded to 15 float4 (240B): read-side lane stride = 60 dwords
// === 28 mod 32 -> 8 disjoint 4-bank windows, 8 accesses/bank = conflict-free.
// 60KB LDS @ 256 thr -> 2 blocks/CU. Output unchanged: qs = round(q)-128,
// halo = -128 (epilogue corrects with +128*tsum[oc]).
// ---------------------------------------------------------------------------
__global__ __launch_bounds__(256)
void act_kernel(const float* __restrict__ x, const float* __restrict__ gamma,
                const float* __restrict__ beta, const float* __restrict__ a_ptr,
                const float* __restrict__ stats, char* __restrict__ q) {
    int by = blockIdx.x;                 // b*58 + y
    int b = by / P_;
    int y = by - b * P_;
    char* qrow = q + (size_t)by * P_ * C_;
    const int PADV = 0x80808080;         // four -128 bytes
    if (y == 0 || y == P_ - 1) {
        int4 pv = {PADV, PADV, PADV, PADV};
        for (int i = threadIdx.x; i < (P_ * C_) / 16; i += 256)
            ((int4*)qrow)[i] = pv;
        return;
    }
    int t = threadIdx.x;
    // halo columns (pixel 0 and 57): 64 ints each
    if (t < 64)            ((int*)qrow)[t] = PADV;
    else if (t < 128)      ((int*)(qrow + (P_ - 1) * C_))[t - 64] = PADV;

    // ---- coalesced stage: x[b, 0..255, y-1, 0..55] -> LDS ------------------
    __shared__ float4 xs[256 * 15];      // 60 KB, padded stride 15
    const float* xb2 = x + (size_t)b * C_ * HW_ + (y - 1) * W_;
    #pragma unroll
    for (int k = 0; k < 14; ++k) {       // 3584 chunks / 256 threads
        int idx = t + k * 256;
        int c   = idx / 14;              // channel
        int jj  = idx - c * 14;          // float4 index within row
        xs[c * 15 + jj] = *(const float4*)(xb2 + (size_t)c * HW_ + jj * 4);
    }
    __syncthreads();

    float a_c = fmaxf(a_ptr[0], 0.f) + 1e-8f;
    float S   = 255.f / a_c;

    int c4 = t & 63;                     // channels 4*c4 .. 4*c4+3 (same group)
    int wb = t >> 6;                     // starting w-block
    int g  = (4 * c4) >> 5;
    float mu = stats[(b * G_ + g) * 2];
    float rs = stats[(b * G_ + g) * 2 + 1];
    float ga[4], be[4];
    #pragma unroll
    for (int i = 0; i < 4; ++i) { ga[i] = gamma[4 * c4 + i]; be[i] = beta[4 * c4 + i]; }

    for (int j = wb; j < 14; j += 4) {
        float4 v[4];
        #pragma unroll
        for (int i = 0; i < 4; ++i)
            v[i] = xs[(4 * c4 + i) * 15 + j];
        int qv[4][4];
        #pragma unroll
        for (int i = 0; i < 4; ++i) {
            float f[4] = {v[i].x, v[i].y, v[i].z, v[i].w};
            #pragma unroll
            for (int s = 0; s < 4; ++s) {
                float yv = (f[s] - mu) * rs * ga[i] + be[i];
                float r  = fmaxf(yv, 0.f);
                float h2 = fminf(r * r, a_c);
                qv[i][s] = (int)rintf(h2 * S) - 128;
            }
        }
        #pragma unroll
        for (int s = 0; s < 4; ++s) {
            int packed = (qv[0][s] & 255) | ((qv[1][s] & 255) << 8) |
                         ((qv[2][s] & 255) << 16) | (qv[3][s] << 24);
            *(int*)(qrow + (j * 4 + s + 1) * C_ + 4 * c4) = packed;
        }
    }
}

// ---------------------------------------------------------------------------
// Kernel 3: ternary weight prep. One block per oc. Writes wt[tap][oc][ic]
// as int8 {-1,0,+1}, alpha[oc], and tsum[oc] = sum_k t[oc,k] (epilogue
// correction for the -128 activation shift).
// ---------------------------------------------------------------------------
__global__ __launch_bounds__(256)
void wq_kernel(const float* __restrict__ wfp, char* __restrict__ wt,
               float* __restrict__ alphas, float* __restrict__ tsum) {
    int oc = blockIdx.x;
    int t  = threadIdx.x;
    const float* wr = wfp + (size_t)oc * KTOT_;
    float wl[9];
    float s = 0.f;
    #pragma unroll
    for (int j = 0; j < 9; ++j) { wl[j] = wr[t + j * 256]; s += fabsf(wl[j]); }

    __shared__ float red[4];
    int lane = t & 63, wv = t >> 6;
    #pragma unroll
    for (int off = 32; off; off >>= 1) s += __shfl_down(s, off, 64);
    if (!lane) red[wv] = s;
    __syncthreads();
    float thr = 0.05f * ((red[0] + red[1] + red[2] + red[3]) / (float)KTOT_);
    __syncthreads();

    float sm = 0.f, cnt = 0.f, ts = 0.f;
    #pragma unroll
    for (int j = 0; j < 9; ++j) {
        float aw = fabsf(wl[j]);
        if (aw > thr) {
            sm += aw; cnt += 1.f;
            ts += (wl[j] > 0.f) ? 1.f : -1.f;
        }
    }
    #pragma unroll
    for (int off = 32; off; off >>= 1) {
        sm  += __shfl_down(sm, off, 64);
        cnt += __shfl_down(cnt, off, 64);
        ts  += __shfl_down(ts, off, 64);
    }
    __shared__ float redc[4], redt[4];
    if (!lane) { red[wv] = sm; redc[wv] = cnt; redt[wv] = ts; }
    __syncthreads();
    if (t == 0) {
        float alpha = (red[0] + red[1] + red[2] + red[3]) /
                      (redc[0] + redc[1] + redc[2] + redc[3] + 1e-8f);
        alphas[oc] = alpha;
        tsum[oc] = redt[0] + redt[1] + redt[2] + redt[3];
    }
    #pragma unroll
    for (int j = 0; j < 9; ++j) {
        int i  = t + j * 256;           // i = ic*9 + tap
        int ic = i / 9;
        int tap = i - ic * 9;
        float w = wl[j];
        char tern = (fabsf(w) > thr) ? (w > 0.f ? (char)1 : (char)-1) : (char)0;
        wt[((size_t)tap * 256 + oc) * 256 + ic] = tern;
    }
}

// ---------------------------------------------------------------------------
// Kernel 4 (v4 = round-0 body + XCD swizzle only): implicit-GEMM conv,
// i8 MFMA. M=100352, N=256 (full N per block), K=9*256. 128x256 block tile,
// BK=128, SINGLE-buffered 48KB LDS. Critical resource fact (r2 post-mortem):
// this body compiles to 64 VGPR + 64 AGPR = 128/wave -> 4 waves/SIMD ->
// 2 blocks/CU; the second resident block provides the pipeline overlap
// (m114). Any dbuf variant pushed VGPR to 128 -> 1 block/CU -> slower.
// XCD swizzle (scalar-only, VGPR-neutral): 784 = 8*98 bijective chunking,
// one XCD's 98 M-tiles span ~3.3MB of qbuf -> fits 4MB per-XCD L2
// (validated r2: FETCH 35 -> 24.5 MB). Epilogue adds 128*tsum[oc].
// ---------------------------------------------------------------------------
__global__ __launch_bounds__(512)
void conv_gemm_kernel(const char* __restrict__ q, const char* __restrict__ wt,
                      const float* __restrict__ alphas, const float* __restrict__ bias,
                      const float* __restrict__ tsum, const float* __restrict__ a_ptr,
                      float* __restrict__ out) {
    int bid = blockIdx.x;
    int mt = (bid & 7) * 98 + (bid >> 3);   // XCD swizzle: bijective, 784 = 8*98
    int tid = threadIdx.x;       // 0..511
    int lane = tid & 63;
    int wv = tid >> 6;           // 0..7
    int wm = wv & 1, wn = wv >> 1;          // 2 m-halves x 4 n-quarters
    int quad = lane >> 4, lrow = lane & 15;

    __shared__ char As[128 * 128];   // 16 KB
    __shared__ char Bs[256 * 128];   // 32 KB

    // XOR bank swizzle on 16B K-blocks: slot kb holds global kb ^ (row&7)
    int kswz = (((tid & 7) ^ ((tid >> 3) & 7)) << 4);
    int sb[2], wb[4];
    #pragma unroll
    for (int r = 0; r < 2; ++r) {
        int ml = r * 64 + (tid >> 3);
        int m = mt * 128 + ml;
        int b = m / HW_;
        int rem = m - b * HW_;
        int hh = rem / W_;
        int ww = rem - hh * W_;
        sb[r] = ((b * P_ + hh + 1) * P_ + (ww + 1)) * C_ + kswz;
    }
    #pragma unroll
    for (int r = 0; r < 4; ++r) {
        int oc = r * 64 + (tid >> 3);
        wb[r] = oc * C_ + kswz;
    }

    i32x4 acc[4][4];
    #pragma unroll
    for (int i = 0; i < 4; ++i)
        #pragma unroll
        for (int j = 0; j < 4; ++j) { acc[i][j][0]=0; acc[i][j][1]=0; acc[i][j][2]=0; acc[i][j][3]=0; }

    int arow = wm * 64 + lrow;
    int brow = wn * 64 + lrow;
    int rsw = lrow & 7;          // read-side XOR key

    for (int kk = 0; kk < 18; ++kk) {
        int tap = kk >> 1;
        int ic0 = (kk & 1) << 7;
        int dh = tap / 3 - 1;
        int dw = tap - (tap / 3) * 3 - 1;
        int aoff = (dh * P_ + dw) * C_ + ic0;
        const char* gb = wt + (size_t)tap * (256 * 256) + ic0;
        #pragma unroll
        for (int r = 0; r < 2; ++r) {
            __builtin_amdgcn_global_load_lds(
                (const __attribute__((address_space(1))) void*)(q + sb[r] + aoff),
                (__attribute__((address_space(3))) void*)(&As[r * 8192 + tid * 16]),
                16, 0, 0);
        }
        #pragma unroll
        for (int r = 0; r < 4; ++r) {
            __builtin_amdgcn_global_load_lds(
                (const __attribute__((address_space(1))) void*)(gb + wb[r]),
                (__attribute__((address_space(3))) void*)(&Bs[r * 8192 + tid * 16]),
                16, 0, 0);
        }
        __syncthreads();
        #pragma unroll
        for (int ks = 0; ks < 2; ++ks) {
            int cb = (ks * 4 + quad) ^ rsw;
            i32x4 af[4], bf[4];
            #pragma unroll
            for (int mi = 0; mi < 4; ++mi)
                af[mi] = *(const i32x4*)&As[(arow + mi * 16) * 128 + cb * 16];
            #pragma unroll
            for (int ni = 0; ni < 4; ++ni)
                bf[ni] = *(const i32x4*)&Bs[(brow + ni * 16) * 128 + cb * 16];
            #pragma unroll
            for (int mi = 0; mi < 4; ++mi)
                #pragma unroll
                for (int ni = 0; ni < 4; ++ni)
                    acc[mi][ni] = __builtin_amdgcn_mfma_i32_16x16x64_i8(
                        af[mi], bf[ni], acc[mi][ni], 0, 0, 0);
        }
        __syncthreads();
    }

    float a_c = fmaxf(a_ptr[0], 0.f) + 1e-8f;
    float qs  = a_c * (1.f / 255.f);
    #pragma unroll
    for (int ni = 0; ni < 4; ++ni) {
        int n = wn * 64 + ni * 16 + lrow;
        float sc = alphas[n] * qs;
        float bn = bias[n];
        float corr = 128.f * tsum[n];       // undo the -128 activation shift
        #pragma unroll
        for (int mi = 0; mi < 4; ++mi) {
            int mbase = mt * 128 + wm * 64 + mi * 16 + quad * 4;
            int b = mbase / HW_;
            size_t off = (size_t)b * (C_ * HW_) + (size_t)n * HW_ + (mbase - b * HW_);
            f32x4 v;
            #pragma unroll
            for (int r = 0; r < 4; ++r)
                v[r] = ((float)acc[mi][ni][r] + corr) * sc + bn;
            *(f32x4*)(out + off) = v;
        }
    }
}

// ---------------------------------------------------------------------------
extern "C" void kernel_launch(void* const* d_in, const int* in_sizes, int n_in,
                              void* d_out, int out_size, void* d_ws, size_t ws_size,
                              hipStream_t stream) {
    const float* x     = (const float*)d_in[0];
    const float* gamma = (const float*)d_in[1];
    const float* beta  = (const float*)d_in[2];
    const float* a     = (const float*)d_in[3];
    const float* wfp   = (const float*)d_in[4];
    const float* bias  = (const float*)d_in[5];
    float* out = (float*)d_out;

    char* ws = (char*)d_ws;
    char*  qbuf   = ws;                                        // 32*58*58*256 i8 = 27,557,888 B
    char*  wtb    = ws + 27557888;                             // 9*256*256 i8  = 589,824 B
    float* alphas = (float*)(ws + 27557888 + 589824);          // 256 fp32
    float* tsum   = alphas + 256;                              // 256 fp32
    float* stats  = tsum + 256;                                // 512 fp32 (mu, rs)

    gn_stats_kernel<<<B_ * G_, 1024, 0, stream>>>(x, stats);
    wq_kernel<<<COUT_, 256, 0, stream>>>(wfp, wtb, alphas, tsum);
    act_kernel<<<B_ * P_, 256, 0, stream>>>(x, gamma, beta, a, stats, qbuf);
    conv_gemm_kernel<<<784, 512, 0, stream>>>(qbuf, wtb, alphas, bias, tsum, a, out);
}

// Round 4
// 279.206 us; speedup vs baseline: 1.2220x; 1.0034x over previous
//
#include <hip/hip_runtime.h>
#include <hip/hip_bf16.h>

#define B_    32
#define C_    256
#define H_    56
#define W_    56
#define HW_   3136
#define P_    58          // padded spatial (halo of 1)
#define G_    8
#define COUT_ 256
#define KTOT_ 2304        // 256 * 9

typedef float f32x4 __attribute__((ext_vector_type(4)));
typedef int   i32x4 __attribute__((ext_vector_type(4)));

// ---------------------------------------------------------------------------
// Kernel 1 (v2: partial reduction at full occupancy). r3 post-mortem: the old
// 256-block version was 1 block/CU, 16 waves, rolled dependent loop -> few
// outstanding loads -> latency-bound (~2 TB/s). v2: 2048 blocks (8/CU, 32
// waves/CU) each reduce a 49KB contiguous 1/8-slab of one (b,g) group into
// float2 partial[2048]. Final 8-way reduction is folded into act_kernel
// (deterministic, no atomics, no extra kernel).
// ---------------------------------------------------------------------------
__global__ __launch_bounds__(256)
void gn_partial_kernel(const float* __restrict__ x, float2* __restrict__ partial) {
    int blk = blockIdx.x;                      // (b*8+g)*8 + sub
    const float4* base = (const float4*)(x + (size_t)blk * 12544);
    float s1 = 0.f, s2 = 0.f;
    for (int i = threadIdx.x; i < 3136; i += 256) {   // 12544 floats / 4
        float4 v = base[i];
        s1 += v.x + v.y + v.z + v.w;
        s2 += v.x * v.x + v.y * v.y + v.z * v.z + v.w * v.w;
    }
    #pragma unroll
    for (int off = 32; off; off >>= 1) {
        s1 += __shfl_down(s1, off, 64);
        s2 += __shfl_down(s2, off, 64);
    }
    __shared__ float ra[4], rb[4];
    int lane = threadIdx.x & 63, wv = threadIdx.x >> 6;
    if (!lane) { ra[wv] = s1; rb[wv] = s2; }
    __syncthreads();
    if (threadIdx.x == 0) {
        float2 p;
        p.x = ra[0] + ra[1] + ra[2] + ra[3];
        p.y = rb[0] + rb[1] + rb[2] + rb[3];
        partial[blk] = p;
    }
}

// ---------------------------------------------------------------------------
// Kernel 2 (v5): GN + ReLU^2 + PACT quant -> zero-padded NHWC int8 buffer.
// Stages the (b, row y-1) slab (256 ch x 56 fl) into LDS, coalesced global
// reads, then quant/register-transpose out of LDS.
// v4's LDS layout (stride 15 fl4) had read-lane stride 240 dw === 16 mod 32:
// 64 lanes -> 2 bank-groups (~4x over minimum). Padding can't fix a 4-row
// step (always === {0,16} mod 32); v5 uses an XOR swizzle at float4
// granularity: element (c, jj) stored at slot jj ^ ((c>>2)&7), row stride 16
// fl4 (256B). Read (c4 lanes, fixed j): block%8 = (j&7)^(c4&7) -> all 8
// bank-groups, standard-throughput b128. Write (lanes jj-major): block%8 =
// (jj&7)^key -> spread. 64KB LDS -> 2 blocks/CU.
// Also computes mu/rs from the 8 gn partials per group (16 cached loads).
// Output unchanged: qs = round(q)-128, halo = -128 (epilogue +128*tsum[oc]).
// ---------------------------------------------------------------------------
__global__ __launch_bounds__(256)
void act_kernel(const float* __restrict__ x, const float* __restrict__ gamma,
                const float* __restrict__ beta, const float* __restrict__ a_ptr,
                const float2* __restrict__ partial, char* __restrict__ q) {
    int by = blockIdx.x;                 // b*58 + y
    int b = by / P_;
    int y = by - b * P_;
    char* qrow = q + (size_t)by * P_ * C_;
    const int PADV = 0x80808080;         // four -128 bytes
    if (y == 0 || y == P_ - 1) {
        int4 pv = {PADV, PADV, PADV, PADV};
        for (int i = threadIdx.x; i < (P_ * C_) / 16; i += 256)
            ((int4*)qrow)[i] = pv;
        return;
    }
    int t = threadIdx.x;
    // halo columns (pixel 0 and 57): 64 ints each
    if (t < 64)            ((int*)qrow)[t] = PADV;
    else if (t < 128)      ((int*)(qrow + (P_ - 1) * C_))[t - 64] = PADV;

    // ---- coalesced stage: x[b, 0..255, y-1, 0..55] -> swizzled LDS ---------
    __shared__ float4 xs[256 * 16];      // 64 KB, stride 16, XOR-swizzled
    const float* xb2 = x + (size_t)b * C_ * HW_ + (y - 1) * W_;
    #pragma unroll
    for (int k = 0; k < 14; ++k) {       // 3584 chunks / 256 threads
        int idx = t + k * 256;
        int c   = idx / 14;              // channel
        int jj  = idx - c * 14;          // float4 index within row
        int key = (c >> 2) & 7;
        xs[c * 16 + (jj ^ key)] = *(const float4*)(xb2 + (size_t)c * HW_ + jj * 4);
    }
    __syncthreads();

    float a_c = fmaxf(a_ptr[0], 0.f) + 1e-8f;
    float S   = 255.f / a_c;

    int c4 = t & 63;                     // channels 4*c4 .. 4*c4+3 (same group)
    int wb = t >> 6;                     // starting w-block
    int g  = c4 >> 3;                    // == (4*c4) >> 5
    // finalize GN stats from the 8 partials of this (b,g) group
    const float2* pp = partial + ((size_t)b * G_ + g) * 8;
    float s1 = 0.f, s2 = 0.f;
    #pragma unroll
    for (int p = 0; p < 8; ++p) { s1 += pp[p].x; s2 += pp[p].y; }
    float mu = s1 / 100352.f;
    float var = s2 / 100352.f - mu * mu;
    float rs = rsqrtf(var + 1e-5f);

    float ga[4], be[4];
    #pragma unroll
    for (int i = 0; i < 4; ++i) { ga[i] = gamma[4 * c4 + i]; be[i] = beta[4 * c4 + i]; }

    int rkey = c4 & 7;                   // read-side XOR key (== ((4c4+i)>>2)&7)
    for (int j = wb; j < 14; j += 4) {
        float4 v[4];
        #pragma unroll
        for (int i = 0; i < 4; ++i)
            v[i] = xs[(4 * c4 + i) * 16 + (j ^ rkey)];
        int qv[4][4];
        #pragma unroll
        for (int i = 0; i < 4; ++i) {
            float f[4] = {v[i].x, v[i].y, v[i].z, v[i].w};
            #pragma unroll
            for (int s = 0; s < 4; ++s) {
                float yv = (f[s] - mu) * rs * ga[i] + be[i];
                float r  = fmaxf(yv, 0.f);
                float h2 = fminf(r * r, a_c);
                qv[i][s] = (int)rintf(h2 * S) - 128;
            }
        }
        #pragma unroll
        for (int s = 0; s < 4; ++s) {
            int packed = (qv[0][s] & 255) | ((qv[1][s] & 255) << 8) |
                         ((qv[2][s] & 255) << 16) | (qv[3][s] << 24);
            *(int*)(qrow + (j * 4 + s + 1) * C_ + 4 * c4) = packed;
        }
    }
}

// ---------------------------------------------------------------------------
// Kernel 3: ternary weight prep. One block per oc. Writes wt[tap][oc][ic]
// as int8 {-1,0,+1}, alpha[oc], and tsum[oc] = sum_k t[oc,k] (epilogue
// correction for the -128 activation shift).
// ---------------------------------------------------------------------------
__global__ __launch_bounds__(256)
void wq_kernel(const float* __restrict__ wfp, char* __restrict__ wt,
               float* __restrict__ alphas, float* __restrict__ tsum) {
    int oc = blockIdx.x;
    int t  = threadIdx.x;
    const float* wr = wfp + (size_t)oc * KTOT_;
    float wl[9];
    float s = 0.f;
    #pragma unroll
    for (int j = 0; j < 9; ++j) { wl[j] = wr[t + j * 256]; s += fabsf(wl[j]); }

    __shared__ float red[4];
    int lane = t & 63, wv = t >> 6;
    #pragma unroll
    for (int off = 32; off; off >>= 1) s += __shfl_down(s, off, 64);
    if (!lane) red[wv] = s;
    __syncthreads();
    float thr = 0.05f * ((red[0] + red[1] + red[2] + red[3]) / (float)KTOT_);
    __syncthreads();

    float sm = 0.f, cnt = 0.f, ts = 0.f;
    #pragma unroll
    for (int j = 0; j < 9; ++j) {
        float aw = fabsf(wl[j]);
        if (aw > thr) {
            sm += aw; cnt += 1.f;
            ts += (wl[j] > 0.f) ? 1.f : -1.f;
        }
    }
    #pragma unroll
    for (int off = 32; off; off >>= 1) {
        sm  += __shfl_down(sm, off, 64);
        cnt += __shfl_down(cnt, off, 64);
        ts  += __shfl_down(ts, off, 64);
    }
    __shared__ float redc[4], redt[4];
    if (!lane) { red[wv] = sm; redc[wv] = cnt; redt[wv] = ts; }
    __syncthreads();
    if (t == 0) {
        float alpha = (red[0] + red[1] + red[2] + red[3]) /
                      (redc[0] + redc[1] + redc[2] + redc[3] + 1e-8f);
        alphas[oc] = alpha;
        tsum[oc] = redt[0] + redt[1] + redt[2] + redt[3];
    }
    #pragma unroll
    for (int j = 0; j < 9; ++j) {
        int i  = t + j * 256;           // i = ic*9 + tap
        int ic = i / 9;
        int tap = i - ic * 9;
        float w = wl[j];
        char tern = (fabsf(w) > thr) ? (w > 0.f ? (char)1 : (char)-1) : (char)0;
        wt[((size_t)tap * 256 + oc) * 256 + ic] = tern;
    }
}

// ---------------------------------------------------------------------------
// Kernel 4 (FROZEN from r3 = round-0 body + XCD swizzle): implicit-GEMM conv,
// i8 MFMA. 128x256 tile, BK=128, single-buffered 48KB LDS. 64 VGPR + 64 AGPR
// -> 2 blocks/CU; second resident block provides pipeline overlap (m114).
// Bijective XCD swizzle 784 = 8*98 (validated: FETCH 35 -> 24.7 MB).
// ---------------------------------------------------------------------------
__global__ __launch_bounds__(512)
void conv_gemm_kernel(const char* __restrict__ q, const char* __restrict__ wt,
                      const float* __restrict__ alphas, const float* __restrict__ bias,
                      const float* __restrict__ tsum, const float* __restrict__ a_ptr,
                      float* __restrict__ out) {
    int bid = blockIdx.x;
    int mt = (bid & 7) * 98 + (bid >> 3);   // XCD swizzle: bijective, 784 = 8*98
    int tid = threadIdx.x;       // 0..511
    int lane = tid & 63;
    int wv = tid >> 6;           // 0..7
    int wm = wv & 1, wn = wv >> 1;          // 2 m-halves x 4 n-quarters
    int quad = lane >> 4, lrow = lane & 15;

    __shared__ char As[128 * 128];   // 16 KB
    __shared__ char Bs[256 * 128];   // 32 KB

    // XOR bank swizzle on 16B K-blocks: slot kb holds global kb ^ (row&7)
    int kswz = (((tid & 7) ^ ((tid >> 3) & 7)) << 4);
    int sb[2], wb[4];
    #pragma unroll
    for (int r = 0; r < 2; ++r) {
        int ml = r * 64 + (tid >> 3);
        int m = mt * 128 + ml;
        int b = m / HW_;
        int rem = m - b * HW_;
        int hh = rem / W_;
        int ww = rem - hh * W_;
        sb[r] = ((b * P_ + hh + 1) * P_ + (ww + 1)) * C_ + kswz;
    }
    #pragma unroll
    for (int r = 0; r < 4; ++r) {
        int oc = r * 64 + (tid >> 3);
        wb[r] = oc * C_ + kswz;
    }

    i32x4 acc[4][4];
    #pragma unroll
    for (int i = 0; i < 4; ++i)
        #pragma unroll
        for (int j = 0; j < 4; ++j) { acc[i][j][0]=0; acc[i][j][1]=0; acc[i][j][2]=0; acc[i][j][3]=0; }

    int arow = wm * 64 + lrow;
    int brow = wn * 64 + lrow;
    int rsw = lrow & 7;          // read-side XOR key

    for (int kk = 0; kk < 18; ++kk) {
        int tap = kk >> 1;
        int ic0 = (kk & 1) << 7;
        int dh = tap / 3 - 1;
        int dw = tap - (tap / 3) * 3 - 1;
        int aoff = (dh * P_ + dw) * C_ + ic0;
        const char* gb = wt + (size_t)tap * (256 * 256) + ic0;
        #pragma unroll
        for (int r = 0; r < 2; ++r) {
            __builtin_amdgcn_global_load_lds(
                (const __attribute__((address_space(1))) void*)(q + sb[r] + aoff),
                (__attribute__((address_space(3))) void*)(&As[r * 8192 + tid * 16]),
                16, 0, 0);
        }
        #pragma unroll
        for (int r = 0; r < 4; ++r) {
            __builtin_amdgcn_global_load_lds(
                (const __attribute__((address_space(1))) void*)(gb + wb[r]),
                (__attribute__((address_space(3))) void*)(&Bs[r * 8192 + tid * 16]),
                16, 0, 0);
        }
        __syncthreads();
        #pragma unroll
        for (int ks = 0; ks < 2; ++ks) {
            int cb = (ks * 4 + quad) ^ rsw;
            i32x4 af[4], bf[4];
            #pragma unroll
            for (int mi = 0; mi < 4; ++mi)
                af[mi] = *(const i32x4*)&As[(arow + mi * 16) * 128 + cb * 16];
            #pragma unroll
            for (int ni = 0; ni < 4; ++ni)
                bf[ni] = *(const i32x4*)&Bs[(brow + ni * 16) * 128 + cb * 16];
            #pragma unroll
            for (int mi = 0; mi < 4; ++mi)
                #pragma unroll
                for (int ni = 0; ni < 4; ++ni)
                    acc[mi][ni] = __builtin_amdgcn_mfma_i32_16x16x64_i8(
                        af[mi], bf[ni], acc[mi][ni], 0, 0, 0);
        }
        __syncthreads();
    }

    float a_c = fmaxf(a_ptr[0], 0.f) + 1e-8f;
    float qs  = a_c * (1.f / 255.f);
    #pragma unroll
    for (int ni = 0; ni < 4; ++ni) {
        int n = wn * 64 + ni * 16 + lrow;
        float sc = alphas[n] * qs;
        float bn = bias[n];
        float corr = 128.f * tsum[n];       // undo the -128 activation shift
        #pragma unroll
        for (int mi = 0; mi < 4; ++mi) {
            int mbase = mt * 128 + wm * 64 + mi * 16 + quad * 4;
            int b = mbase / HW_;
            size_t off = (size_t)b * (C_ * HW_) + (size_t)n * HW_ + (mbase - b * HW_);
            f32x4 v;
            #pragma unroll
            for (int r = 0; r < 4; ++r)
                v[r] = ((float)acc[mi][ni][r] + corr) * sc + bn;
            *(f32x4*)(out + off) = v;
        }
    }
}

// ---------------------------------------------------------------------------
extern "C" void kernel_launch(void* const* d_in, const int* in_sizes, int n_in,
                              void* d_out, int out_size, void* d_ws, size_t ws_size,
                              hipStream_t stream) {
    const float* x     = (const float*)d_in[0];
    const float* gamma = (const float*)d_in[1];
    const float* beta  = (const float*)d_in[2];
    const float* a     = (const float*)d_in[3];
    const float* wfp   = (const float*)d_in[4];
    const float* bias  = (const float*)d_in[5];
    float* out = (float*)d_out;

    char* ws = (char*)d_ws;
    char*   qbuf    = ws;                                      // 32*58*58*256 i8 = 27,557,888 B
    char*   wtb     = ws + 27557888;                           // 9*256*256 i8  = 589,824 B
    float*  alphas  = (float*)(ws + 27557888 + 589824);        // 256 fp32
    float*  tsum    = alphas + 256;                            // 256 fp32
    float2* partial = (float2*)(tsum + 256);                   // 2048 float2 = 16 KB

    gn_partial_kernel<<<2048, 256, 0, stream>>>(x, partial);
    wq_kernel<<<COUT_, 256, 0, stream>>>(wfp, wtb, alphas, tsum);
    act_kernel<<<B_ * P_, 256, 0, stream>>>(x, gamma, beta, a, partial, qbuf);
    conv_gemm_kernel<<<784, 512, 0, stream>>>(qbuf, wtb, alphas, bias, tsum, a, out);
}